// Round 1
// baseline (3510.900 us; speedup 1.0000x reference)
//
#include <hip/hip_runtime.h>
#include <stdint.h>

#define BETA 0.9f

// ---------------------------------------------------------------------------
// Kernel 1: transpose fw1 (256, 1152) -> fw1T (1152, 256) so the sparse fc1
// row-gather is coalesced (row i = 256 contiguous floats = 1KB per wave read).
// ---------------------------------------------------------------------------
__global__ void transpose_fw1(const float* __restrict__ A, float* __restrict__ At) {
    __shared__ float tile[32][33];
    const int i0 = blockIdx.x * 32;   // i dim (1152)
    const int j0 = blockIdx.y * 32;   // j dim (256)
    const int tx = threadIdx.x, ty = threadIdx.y;
    for (int r = ty; r < 32; r += 8)
        tile[r][tx] = A[(j0 + r) * 1152 + i0 + tx];      // coalesced read over i
    __syncthreads();
    for (int r = ty; r < 32; r += 8)
        At[(i0 + r) * 256 + j0 + tx] = tile[tx][r];      // coalesced write over j
}

// ---------------------------------------------------------------------------
// Kernel 2: the whole SNN, one block (256 threads) per batch element,
// T-loop inside the block. Membrane state lives in registers of the thread
// that owns each neuron; spike buffers live in LDS; conv weights live in
// per-lane VGPRs (lane <-> output channel).
// ---------------------------------------------------------------------------
__global__ __launch_bounds__(256, 2) void snn_main(
    const float* __restrict__ x,      // (1024, 1, 30, 100)
    const float* __restrict__ w1, const float* __restrict__ b1,
    const float* __restrict__ w2, const float* __restrict__ b2,
    const float* __restrict__ w3, const float* __restrict__ b3,
    const float* __restrict__ fw1T,   // (1152, 256) transposed
    const float* __restrict__ fb1,
    const float* __restrict__ fw2, const float* __restrict__ fb2,
    float* __restrict__ out)          // (100, 1024, 10)
{
    const int b    = blockIdx.x;
    const int tid  = threadIdx.x;
    const int lane = tid & 63;
    const int wave = tid >> 6;

    __shared__ float xbuf[30];
    __shared__ float s1[16 * 24 + 8];   // +pad, zeroed (conv2 window over-read)
    __shared__ float s2[32 * 20 + 8];   // +pad, zeroed (conv3 window over-read)
    __shared__ unsigned long long masks[18];  // s3 spike bitmask per l (bit = channel)
    __shared__ float s4[256];
    __shared__ float parts[80];

    // ---- static per-thread roles ----
    const int c1 = tid & 15;            // conv1: channel
    const int l1 = tid >> 4;            // conv1: l (0..15); second output l1+16 for tid<128
    const int c2 = tid & 31;            // conv2: channel
    const int lg2 = tid >> 5;           // conv2: l-group 0..7
    const int l02 = (lg2 < 4) ? 3 * lg2 : 12 + 2 * (lg2 - 4);
    const int nl2 = (lg2 < 4) ? 3 : 2;  // wave-uniform (lg pairs per wave)
    const int c3 = lane;                // conv3: channel = lane (ballot gives mask by channel)
    const int l03 = wave * 5;           // conv3: l-range start (wave-uniform)
    const int nl3 = (wave < 3) ? 5 : 3; // 5,5,5,3 -> 18

    if (tid < 8) { s1[384 + tid] = 0.0f; s2[640 + tid] = 0.0f; }

    // ---- weights into registers (reused 100 steps) ----
    float w1r[7];
#pragma unroll
    for (int k = 0; k < 7; ++k) w1r[k] = w1[c1 * 7 + k];
    const float b1r = b1[c1];
    float w2r[16][5];
#pragma unroll
    for (int ci = 0; ci < 16; ++ci)
#pragma unroll
        for (int k = 0; k < 5; ++k) w2r[ci][k] = w2[c2 * 80 + ci * 5 + k];
    const float b2r = b2[c2];
    float w3r[32][3];
#pragma unroll
    for (int ci = 0; ci < 32; ++ci)
#pragma unroll
        for (int k = 0; k < 3; ++k) w3r[ci][k] = w3[c3 * 96 + ci * 3 + k];
    const float b3r = b3[c3];
    const float fb1r = fb1[tid];
    const float fb2r = (tid < 10) ? fb2[tid] : 0.0f;

    // ---- membrane state in registers ----
    float m1a = 0.f, m1b = 0.f;
    float m2[3] = {0.f, 0.f, 0.f};
    float m3[5] = {0.f, 0.f, 0.f, 0.f, 0.f};
    float m4 = 0.f, m5 = 0.f;

    const float* xb = x + b * 3000;
    const int out_b = b * 10;

    for (int t = 0; t < 100; ++t) {
        if (tid < 30) xbuf[tid] = xb[tid * 100 + t];
        __syncthreads();

        // ---- conv1 + LIF1 (dense input) ----
        {
            float h = b1r;
#pragma unroll
            for (int k = 0; k < 7; ++k) h += xbuf[l1 + k] * w1r[k];
            float rs = (m1a > 1.0f) ? 1.0f : 0.0f;
            m1a = BETA * m1a + h - rs;
            s1[c1 * 24 + l1] = (m1a > 1.0f) ? 1.0f : 0.0f;
            if (tid < 128) {
                float h2 = b1r;
#pragma unroll
                for (int k = 0; k < 7; ++k) h2 += xbuf[16 + l1 + k] * w1r[k];
                float r2 = (m1b > 1.0f) ? 1.0f : 0.0f;
                m1b = BETA * m1b + h2 - r2;
                s1[c1 * 24 + 16 + l1] = (m1b > 1.0f) ? 1.0f : 0.0f;
            }
        }
        __syncthreads();

        // ---- conv2 + LIF2 (spike input, wave-level silent-row skip) ----
        {
            float h[3] = {b2r, b2r, b2r};
#pragma unroll
            for (int ci = 0; ci < 16; ++ci) {
                float win[7];
                bool nz = false;
#pragma unroll
                for (int r = 0; r < 7; ++r) {
                    win[r] = s1[ci * 24 + l02 + r];
                    nz |= (win[r] != 0.0f);
                }
                if (__ballot(nz) == 0ull) continue;   // exact: skipped terms are 0*w
#pragma unroll
                for (int li = 0; li < 3; ++li)
                    if (li < nl2)
#pragma unroll
                        for (int k = 0; k < 5; ++k) h[li] += win[li + k] * w2r[ci][k];
            }
#pragma unroll
            for (int li = 0; li < 3; ++li)
                if (li < nl2) {
                    float rs = (m2[li] > 1.0f) ? 1.0f : 0.0f;
                    m2[li] = BETA * m2[li] + h[li] - rs;
                    s2[c2 * 20 + l02 + li] = (m2[li] > 1.0f) ? 1.0f : 0.0f;
                }
        }
        __syncthreads();

        // ---- conv3 + LIF3 -> spike bitmasks (wave-uniform windows) ----
        {
            float h[5] = {b3r, b3r, b3r, b3r, b3r};
#pragma unroll
            for (int ci = 0; ci < 32; ++ci) {
                float win[7];
                bool nz = false;
#pragma unroll
                for (int r = 0; r < 7; ++r) {
                    win[r] = s2[ci * 20 + l03 + r];
                    nz |= (win[r] != 0.0f);
                }
                if (__ballot(nz) == 0ull) continue;
#pragma unroll
                for (int li = 0; li < 5; ++li)
                    if (li < nl3)
#pragma unroll
                        for (int k = 0; k < 3; ++k) h[li] += win[li + k] * w3r[ci][k];
            }
#pragma unroll
            for (int li = 0; li < 5; ++li)
                if (li < nl3) {   // wave-uniform -> ballot safe
                    float rs = (m3[li] > 1.0f) ? 1.0f : 0.0f;
                    m3[li] = BETA * m3[li] + h[li] - rs;
                    float s = (m3[li] > 1.0f) ? 1.0f : 0.0f;
                    unsigned long long mk = __ballot(s != 0.0f);  // bit c3 = spike(c3, l)
                    if (lane == 0) masks[l03 + li] = mk;
                }
        }
        __syncthreads();

        // ---- fc1 sparse: h[j] = fb1[j] + sum over active i of fw1T[i][j] ----
        {
            float acc = fb1r;
#pragma unroll 1
            for (int l = 0; l < 18; ++l) {
                unsigned long long mk = masks[l];
                while (mk) {   // uniform across block; 4-wide load batching
                    float f0 = 0.f, f1 = 0.f, f2 = 0.f, f3 = 0.f;
                    int c;
                    c = (int)__builtin_ctzll(mk); mk &= mk - 1;
                    f0 = fw1T[(c * 18 + l) * 256 + tid];
                    if (mk) { c = (int)__builtin_ctzll(mk); mk &= mk - 1;
                              f1 = fw1T[(c * 18 + l) * 256 + tid]; }
                    if (mk) { c = (int)__builtin_ctzll(mk); mk &= mk - 1;
                              f2 = fw1T[(c * 18 + l) * 256 + tid]; }
                    if (mk) { c = (int)__builtin_ctzll(mk); mk &= mk - 1;
                              f3 = fw1T[(c * 18 + l) * 256 + tid]; }
                    acc += f0; acc += f1; acc += f2; acc += f3;  // +0.0 is exact
                }
            }
            float rs = (m4 > 1.0f) ? 1.0f : 0.0f;
            m4 = BETA * m4 + acc - rs;
            s4[tid] = (m4 > 1.0f) ? 1.0f : 0.0f;
        }
        __syncthreads();

        // ---- fc2: 10 outputs, 8 partial chunks of 32 each ----
        if (tid < 80) {
            const int j = tid >> 3, ch = tid & 7;
            const float* wrow = fw2 + j * 256 + ch * 32;
            const float* srow = s4 + ch * 32;
            float p = 0.f;
#pragma unroll
            for (int i = 0; i < 32; ++i) p += srow[i] * wrow[i];
            parts[tid] = p;
        }
        __syncthreads();
        if (tid < 10) {
            float h = fb2r;
#pragma unroll
            for (int cpt = 0; cpt < 8; ++cpt) h += parts[tid * 8 + cpt];
            float rs = (m5 > 1.0f) ? 1.0f : 0.0f;
            m5 = BETA * m5 + h - rs;
            out[t * 10240 + out_b + tid] = (m5 > 1.0f) ? 1.0f : 0.0f;
        }
        __syncthreads();   // protect parts/s-buffers before next step's writes
    }
}

extern "C" void kernel_launch(void* const* d_in, const int* in_sizes, int n_in,
                              void* d_out, int out_size, void* d_ws, size_t ws_size,
                              hipStream_t stream) {
    const float* x   = (const float*)d_in[0];
    const float* w1  = (const float*)d_in[1];
    const float* b1  = (const float*)d_in[2];
    const float* w2  = (const float*)d_in[3];
    const float* b2  = (const float*)d_in[4];
    const float* w3  = (const float*)d_in[5];
    const float* b3  = (const float*)d_in[6];
    const float* fw1 = (const float*)d_in[7];
    const float* fb1 = (const float*)d_in[8];
    const float* fw2 = (const float*)d_in[9];
    const float* fb2 = (const float*)d_in[10];
    float* out  = (float*)d_out;
    float* fw1T = (float*)d_ws;   // 1152*256*4 = 1.18 MB

    dim3 tb(32, 8);
    dim3 tg(1152 / 32, 256 / 32);
    transpose_fw1<<<tg, tb, 0, stream>>>(fw1, fw1T);
    snn_main<<<1024, 256, 0, stream>>>(x, w1, b1, w2, b2, w3, b3,
                                       fw1T, fb1, fw2, fb2, out);
}

// Round 2
// 1930.694 us; speedup vs baseline: 1.8185x; 1.8185x over previous
//
#include <hip/hip_runtime.h>
#include <stdint.h>

#define BETA 0.9f

// ---------------------------------------------------------------------------
// Kernel 1: transpose fw1 (256, 1152) -> fw1T (1152, 256) so the sparse fc1
// row-gather is coalesced (row i = 256 contiguous floats = 1KB per wave read).
// ---------------------------------------------------------------------------
__global__ void transpose_fw1(const float* __restrict__ A, float* __restrict__ At) {
    __shared__ float tile[32][33];
    const int i0 = blockIdx.x * 32;   // i dim (1152)
    const int j0 = blockIdx.y * 32;   // j dim (256)
    const int tx = threadIdx.x, ty = threadIdx.y;
    for (int r = ty; r < 32; r += 8)
        tile[r][tx] = A[(j0 + r) * 1152 + i0 + tx];      // coalesced read over i
    __syncthreads();
    for (int r = ty; r < 32; r += 8)
        At[(i0 + r) * 256 + j0 + tx] = tile[tx][r];      // coalesced write over j
}

// ---------------------------------------------------------------------------
// Kernel 2: whole SNN, one block (256 threads) per batch element, T-loop in
// the block. R2 change: conv weights live in LDS with lane-transposed layouts
// (broadcast / stride-1 reads, no VGPR arrays -> no scratch spills), and the
// block's x-slice is staged to LDS once (no global reads in the T-loop except
// the fc1 spike gather and fc2 weights).
// ---------------------------------------------------------------------------
__global__ __launch_bounds__(256, 2) void snn_main(
    const float* __restrict__ x,      // (1024, 1, 30, 100)
    const float* __restrict__ w1, const float* __restrict__ b1,
    const float* __restrict__ w2, const float* __restrict__ b2,
    const float* __restrict__ w3, const float* __restrict__ b3,
    const float* __restrict__ fw1T,   // (1152, 256) transposed
    const float* __restrict__ fb1,
    const float* __restrict__ fw2, const float* __restrict__ fb2,
    float* __restrict__ out)          // (100, 1024, 10)
{
    const int b    = blockIdx.x;
    const int tid  = threadIdx.x;
    const int lane = tid & 63;
    const int wave = tid >> 6;

    __shared__ float xL[3000];          // x slice, layout [l][t] (as in global)
    __shared__ float s1[16 * 24 + 8];   // +pad (conv2 lg2=7 window over-read)
    __shared__ float s2[32 * 20 + 8];   // +pad (conv3 wave-3 window over-read)
    __shared__ float w2L[16 * 5 * 32];  // [(ci*5+k)*32 + c2]
    __shared__ float w3L[32 * 3 * 64];  // [(ci*3+k)*64 + c3]
    __shared__ unsigned long long masks[18];  // s3 spike bitmask per l (bit = channel)
    __shared__ float s4[256];
    __shared__ float parts[80];

    // ---- static per-thread roles ----
    const int c1 = tid & 15;            // conv1: channel
    const int l1 = tid >> 4;            // conv1: l (0..15); second output l1+16 for tid<128
    const int c2 = tid & 31;            // conv2: channel
    const int lg2 = tid >> 5;           // conv2: l-group 0..7
    const int l02 = (lg2 < 4) ? 3 * lg2 : 12 + 2 * (lg2 - 4);
    const int nl2 = (lg2 < 4) ? 3 : 2;  // wave-uniform within half-wave groups
    const int c3 = lane;                // conv3: channel = lane (ballot -> mask by channel)
    const int l03 = wave * 5;           // conv3: l-range start (wave-uniform)
    const int nl3 = (wave < 3) ? 5 : 3; // 5,5,5,3 -> 18

    // ---- stage weights + x into LDS (lane-transposed layouts) ----
    const float* xb = x + b * 3000;
    for (int i = tid; i < 3000; i += 256) xL[i] = xb[i];
    for (int i = tid; i < 16 * 5 * 32; i += 256) {
        const int cc = i & 31, r = i >> 5;          // r = ci*5+k
        w2L[i] = w2[cc * 80 + r];
    }
    for (int i = tid; i < 32 * 3 * 64; i += 256) {
        const int cc = i & 63, r = i >> 6;          // r = ci*3+k
        w3L[i] = w3[cc * 96 + r];
    }
    if (tid < 8) { s1[384 + tid] = 0.0f; s2[640 + tid] = 0.0f; }

    // ---- small per-thread register state ----
    float w1r[7];
#pragma unroll
    for (int k = 0; k < 7; ++k) w1r[k] = w1[c1 * 7 + k];
    const float b1r = b1[c1];
    const float b2r = b2[c2];
    const float b3r = b3[c3];
    const float fb1r = fb1[tid];
    const float fb2r = (tid < 10) ? fb2[tid] : 0.0f;

    float m1a = 0.f, m1b = 0.f;
    float m2[3] = {0.f, 0.f, 0.f};
    float m3[5] = {0.f, 0.f, 0.f, 0.f, 0.f};
    float m4 = 0.f, m5 = 0.f;

    const int out_b = b * 10;
    __syncthreads();   // staging -> compute

    for (int t = 0; t < 100; ++t) {
        // ---- conv1 + LIF1 (dense input from LDS xL) ----
        {
            float h = b1r;
#pragma unroll
            for (int k = 0; k < 7; ++k) h += xL[(l1 + k) * 100 + t] * w1r[k];
            float rs = (m1a > 1.0f) ? 1.0f : 0.0f;
            m1a = BETA * m1a + h - rs;
            s1[c1 * 24 + l1] = (m1a > 1.0f) ? 1.0f : 0.0f;
            if (tid < 128) {
                float h2 = b1r;
#pragma unroll
                for (int k = 0; k < 7; ++k) h2 += xL[(16 + l1 + k) * 100 + t] * w1r[k];
                float r2 = (m1b > 1.0f) ? 1.0f : 0.0f;
                m1b = BETA * m1b + h2 - r2;
                s1[c1 * 24 + 16 + l1] = (m1b > 1.0f) ? 1.0f : 0.0f;
            }
        }
        __syncthreads();

        // ---- conv2 + LIF2 (spike input, wave-level silent-row skip) ----
        {
            float h[3] = {b2r, b2r, b2r};
#pragma unroll
            for (int ci = 0; ci < 16; ++ci) {
                float win[7];
                bool nz = false;
#pragma unroll
                for (int r = 0; r < 7; ++r) {
                    win[r] = s1[ci * 24 + l02 + r];
                    nz |= (win[r] != 0.0f);
                }
                if (__ballot(nz) == 0ull) continue;   // exact: skipped terms are 0*w
                float wk[5];
#pragma unroll
                for (int k = 0; k < 5; ++k) wk[k] = w2L[(ci * 5 + k) * 32 + c2];
#pragma unroll
                for (int li = 0; li < 3; ++li)
                    if (li < nl2)
#pragma unroll
                        for (int k = 0; k < 5; ++k) h[li] += win[li + k] * wk[k];
            }
#pragma unroll
            for (int li = 0; li < 3; ++li)
                if (li < nl2) {
                    float rs = (m2[li] > 1.0f) ? 1.0f : 0.0f;
                    m2[li] = BETA * m2[li] + h[li] - rs;
                    s2[c2 * 20 + l02 + li] = (m2[li] > 1.0f) ? 1.0f : 0.0f;
                }
        }
        __syncthreads();

        // ---- conv3 + LIF3 -> spike bitmasks (wave-uniform windows) ----
        {
            float h[5] = {b3r, b3r, b3r, b3r, b3r};
#pragma unroll
            for (int ci = 0; ci < 32; ++ci) {
                float win[7];
                bool nz = false;
#pragma unroll
                for (int r = 0; r < 7; ++r) {
                    win[r] = s2[ci * 20 + l03 + r];
                    nz |= (win[r] != 0.0f);
                }
                if (__ballot(nz) == 0ull) continue;
                float wk[3];
#pragma unroll
                for (int k = 0; k < 3; ++k) wk[k] = w3L[(ci * 3 + k) * 64 + c3];
#pragma unroll
                for (int li = 0; li < 5; ++li)
                    if (li < nl3)
#pragma unroll
                        for (int k = 0; k < 3; ++k) h[li] += win[li + k] * wk[k];
            }
#pragma unroll
            for (int li = 0; li < 5; ++li)
                if (li < nl3) {   // wave-uniform -> ballot safe
                    float rs = (m3[li] > 1.0f) ? 1.0f : 0.0f;
                    m3[li] = BETA * m3[li] + h[li] - rs;
                    float s = (m3[li] > 1.0f) ? 1.0f : 0.0f;
                    unsigned long long mk = __ballot(s != 0.0f);  // bit c3 = spike(c3, l)
                    if (lane == 0) masks[l03 + li] = mk;
                }
        }
        __syncthreads();

        // ---- fc1 sparse: h[j] = fb1[j] + sum over active i of fw1T[i][j] ----
        {
            float acc = fb1r;
#pragma unroll 1
            for (int l = 0; l < 18; ++l) {
                unsigned long long mk = masks[l];
                while (mk) {   // uniform across block; 4-wide load batching
                    float f0 = 0.f, f1 = 0.f, f2 = 0.f, f3 = 0.f;
                    int c;
                    c = (int)__builtin_ctzll(mk); mk &= mk - 1;
                    f0 = fw1T[(c * 18 + l) * 256 + tid];
                    if (mk) { c = (int)__builtin_ctzll(mk); mk &= mk - 1;
                              f1 = fw1T[(c * 18 + l) * 256 + tid]; }
                    if (mk) { c = (int)__builtin_ctzll(mk); mk &= mk - 1;
                              f2 = fw1T[(c * 18 + l) * 256 + tid]; }
                    if (mk) { c = (int)__builtin_ctzll(mk); mk &= mk - 1;
                              f3 = fw1T[(c * 18 + l) * 256 + tid]; }
                    acc += f0; acc += f1; acc += f2; acc += f3;  // +0.0 is exact
                }
            }
            float rs = (m4 > 1.0f) ? 1.0f : 0.0f;
            m4 = BETA * m4 + acc - rs;
            s4[tid] = (m4 > 1.0f) ? 1.0f : 0.0f;
        }
        __syncthreads();

        // ---- fc2: 10 outputs, 8 partial chunks of 32 each ----
        if (tid < 80) {
            const int j = tid >> 3, ch = tid & 7;
            const float* wrow = fw2 + j * 256 + ch * 32;
            const float* srow = s4 + ch * 32;
            float p = 0.f;
#pragma unroll
            for (int i = 0; i < 32; ++i) p += srow[i] * wrow[i];
            parts[tid] = p;
        }
        __syncthreads();
        if (tid < 10) {
            float h = fb2r;
#pragma unroll
            for (int cpt = 0; cpt < 8; ++cpt) h += parts[tid * 8 + cpt];
            float rs = (m5 > 1.0f) ? 1.0f : 0.0f;
            m5 = BETA * m5 + h - rs;
            out[t * 10240 + out_b + tid] = (m5 > 1.0f) ? 1.0f : 0.0f;
        }
        __syncthreads();   // protect parts/s-buffers before next step's writes
    }
}

extern "C" void kernel_launch(void* const* d_in, const int* in_sizes, int n_in,
                              void* d_out, int out_size, void* d_ws, size_t ws_size,
                              hipStream_t stream) {
    const float* x   = (const float*)d_in[0];
    const float* w1  = (const float*)d_in[1];
    const float* b1  = (const float*)d_in[2];
    const float* w2  = (const float*)d_in[3];
    const float* b2  = (const float*)d_in[4];
    const float* w3  = (const float*)d_in[5];
    const float* b3  = (const float*)d_in[6];
    const float* fw1 = (const float*)d_in[7];
    const float* fb1 = (const float*)d_in[8];
    const float* fw2 = (const float*)d_in[9];
    const float* fb2 = (const float*)d_in[10];
    float* out  = (float*)d_out;
    float* fw1T = (float*)d_ws;   // 1152*256*4 = 1.18 MB

    dim3 tb(32, 8);
    dim3 tg(1152 / 32, 256 / 32);
    transpose_fw1<<<tg, tb, 0, stream>>>(fw1, fw1T);
    snn_main<<<1024, 256, 0, stream>>>(x, w1, b1, w2, b2, w3, b3,
                                       fw1T, fb1, fw2, fb2, out);
}

// Round 3
// 1192.404 us; speedup vs baseline: 2.9444x; 1.6192x over previous
//
#include <hip/hip_runtime.h>
#include <stdint.h>

#define BETA 0.9f

// ---------------------------------------------------------------------------
// Kernel 1: transpose fw1 (256, 1152) -> fw1T (1152, 256) so the sparse fc1
// row-gather is coalesced (row i = 256 contiguous floats = 1KB per wave read).
// ---------------------------------------------------------------------------
__global__ void transpose_fw1(const float* __restrict__ A, float* __restrict__ At) {
    __shared__ float tile[32][33];
    const int i0 = blockIdx.x * 32;   // i dim (1152)
    const int j0 = blockIdx.y * 32;   // j dim (256)
    const int tx = threadIdx.x, ty = threadIdx.y;
    for (int r = ty; r < 32; r += 8)
        tile[r][tx] = A[(j0 + r) * 1152 + i0 + tx];      // coalesced read over i
    __syncthreads();
    for (int r = ty; r < 32; r += 8)
        At[(i0 + r) * 256 + j0 + tx] = tile[tx][r];      // coalesced write over j
}

// ---------------------------------------------------------------------------
// Kernel 2: whole SNN, one block (256 threads) per batch element, T-loop in
// the block. R3: LDS cut to ~40.4KB (x read from global with register
// prefetch instead of a 12KB LDS stage) + __launch_bounds__(256,4) so all
// 4 blocks/CU are co-resident (occupancy 25%->50%); fc1 gather batching 8.
// ---------------------------------------------------------------------------
__global__ __launch_bounds__(256, 4) void snn_main(
    const float* __restrict__ x,      // (1024, 1, 30, 100)
    const float* __restrict__ w1, const float* __restrict__ b1,
    const float* __restrict__ w2, const float* __restrict__ b2,
    const float* __restrict__ w3, const float* __restrict__ b3,
    const float* __restrict__ fw1T,   // (1152, 256) transposed
    const float* __restrict__ fb1,
    const float* __restrict__ fw2, const float* __restrict__ fb2,
    float* __restrict__ out)          // (100, 1024, 10)
{
    const int b    = blockIdx.x;
    const int tid  = threadIdx.x;
    const int lane = tid & 63;
    const int wave = tid >> 6;

    __shared__ float s1[16 * 24 + 4];   // +pad (conv2 lg2=7 nz over-read)
    __shared__ float s2[32 * 20 + 4];   // +pad (conv3 wave-3 nz over-read)
    __shared__ float w2L[16 * 5 * 32];  // [(ci*5+k)*32 + c2]  10 KB
    __shared__ float w3L[32 * 3 * 64];  // [(ci*3+k)*64 + c3]  24 KB
    __shared__ unsigned long long masks[18];  // s3 spike bitmask per l (bit = channel)
    __shared__ float s4[256];
    __shared__ float parts[80];

    // ---- static per-thread roles ----
    const int c1 = tid & 15;            // conv1: channel
    const int l1 = tid >> 4;            // conv1: l (0..15); second output l1+16 for tid<128
    const int c2 = tid & 31;            // conv2: channel
    const int lg2 = tid >> 5;           // conv2: l-group 0..7
    const int l02 = (lg2 < 4) ? 3 * lg2 : 12 + 2 * (lg2 - 4);
    const int nl2 = (lg2 < 4) ? 3 : 2;  // uniform within half-wave groups
    const int c3 = lane;                // conv3: channel = lane (ballot -> mask by channel)
    const int l03 = wave * 5;           // conv3: l-range start (wave-uniform)
    const int nl3 = (wave < 3) ? 5 : 3; // 5,5,5,3 -> 18

    // ---- stage weights into LDS (lane-transposed layouts) ----
    for (int i = tid; i < 16 * 5 * 32; i += 256) {
        const int cc = i & 31, r = i >> 5;          // r = ci*5+k
        w2L[i] = w2[cc * 80 + r];
    }
    for (int i = tid; i < 32 * 3 * 64; i += 256) {
        const int cc = i & 63, r = i >> 6;          // r = ci*3+k
        w3L[i] = w3[cc * 96 + r];
    }
    if (tid < 4) { s1[384 + tid] = 0.0f; s2[640 + tid] = 0.0f; }

    // ---- small per-thread register state ----
    float w1r[7];
#pragma unroll
    for (int k = 0; k < 7; ++k) w1r[k] = w1[c1 * 7 + k];
    const float b1r = b1[c1];
    const float b2r = b2[c2];
    const float b3r = b3[c3];
    const float fb1r = fb1[tid];
    const float fb2r = (tid < 10) ? fb2[tid] : 0.0f;

    float m1a = 0.f, m1b = 0.f;
    float m2[3] = {0.f, 0.f, 0.f};
    float m3[5] = {0.f, 0.f, 0.f, 0.f, 0.f};
    float m4 = 0.f, m5 = 0.f;

    const float* xb = x + b * 3000;
    const int out_b = b * 10;

    // x register prefetch for t=0 (loads overlap the staging barrier)
    float xr[7], xr2[7];
#pragma unroll
    for (int k = 0; k < 7; ++k) xr[k] = xb[(l1 + k) * 100];
#pragma unroll
    for (int k = 0; k < 7; ++k) xr2[k] = (tid < 128) ? xb[(16 + l1 + k) * 100] : 0.0f;

    __syncthreads();   // staging -> compute

    for (int t = 0; t < 100; ++t) {
        // ---- conv1 + LIF1 (x from prefetched registers) ----
        {
            float h = b1r;
#pragma unroll
            for (int k = 0; k < 7; ++k) h += xr[k] * w1r[k];
            float rs = (m1a > 1.0f) ? 1.0f : 0.0f;
            m1a = BETA * m1a + h - rs;
            s1[c1 * 24 + l1] = (m1a > 1.0f) ? 1.0f : 0.0f;
            if (tid < 128) {
                float h2 = b1r;
#pragma unroll
                for (int k = 0; k < 7; ++k) h2 += xr2[k] * w1r[k];
                float r2 = (m1b > 1.0f) ? 1.0f : 0.0f;
                m1b = BETA * m1b + h2 - r2;
                s1[c1 * 24 + 16 + l1] = (m1b > 1.0f) ? 1.0f : 0.0f;
            }
        }
        // prefetch x for t+1 (hidden under conv2..fc2 of this step)
        {
            const int tt = (t < 99) ? t + 1 : 99;
#pragma unroll
            for (int k = 0; k < 7; ++k) xr[k] = xb[(l1 + k) * 100 + tt];
            if (tid < 128) {
#pragma unroll
                for (int k = 0; k < 7; ++k) xr2[k] = xb[(16 + l1 + k) * 100 + tt];
            }
        }
        __syncthreads();

        // ---- conv2 + LIF2 (spike input, wave-level silent-row skip) ----
        {
            float h[3] = {b2r, b2r, b2r};
#pragma unroll
            for (int ci = 0; ci < 16; ++ci) {
                float win[7];
                bool nz = false;
#pragma unroll
                for (int r = 0; r < 7; ++r) {
                    win[r] = s1[ci * 24 + l02 + r];
                    nz |= (win[r] != 0.0f);
                }
                if (__ballot(nz) == 0ull) continue;   // exact: skipped terms are 0*w
                float wk[5];
#pragma unroll
                for (int k = 0; k < 5; ++k) wk[k] = w2L[(ci * 5 + k) * 32 + c2];
#pragma unroll
                for (int li = 0; li < 3; ++li)
                    if (li < nl2)
#pragma unroll
                        for (int k = 0; k < 5; ++k) h[li] += win[li + k] * wk[k];
            }
#pragma unroll
            for (int li = 0; li < 3; ++li)
                if (li < nl2) {
                    float rs = (m2[li] > 1.0f) ? 1.0f : 0.0f;
                    m2[li] = BETA * m2[li] + h[li] - rs;
                    s2[c2 * 20 + l02 + li] = (m2[li] > 1.0f) ? 1.0f : 0.0f;
                }
        }
        __syncthreads();

        // ---- conv3 + LIF3 -> spike bitmasks (wave-uniform windows) ----
        {
            float h[5] = {b3r, b3r, b3r, b3r, b3r};
#pragma unroll
            for (int ci = 0; ci < 32; ++ci) {
                float win[7];
                bool nz = false;
#pragma unroll
                for (int r = 0; r < 7; ++r) {
                    win[r] = s2[ci * 20 + l03 + r];
                    nz |= (win[r] != 0.0f);
                }
                if (__ballot(nz) == 0ull) continue;
                float wk[3];
#pragma unroll
                for (int k = 0; k < 3; ++k) wk[k] = w3L[(ci * 3 + k) * 64 + c3];
#pragma unroll
                for (int li = 0; li < 5; ++li)
                    if (li < nl3)
#pragma unroll
                        for (int k = 0; k < 3; ++k) h[li] += win[li + k] * wk[k];
            }
#pragma unroll
            for (int li = 0; li < 5; ++li)
                if (li < nl3) {   // wave-uniform -> ballot safe
                    float rs = (m3[li] > 1.0f) ? 1.0f : 0.0f;
                    m3[li] = BETA * m3[li] + h[li] - rs;
                    float s = (m3[li] > 1.0f) ? 1.0f : 0.0f;
                    unsigned long long mk = __ballot(s != 0.0f);  // bit c3 = spike(c3, l)
                    if (lane == 0) masks[l03 + li] = mk;
                }
        }
        __syncthreads();

        // ---- fc1 sparse: h[j] = fb1[j] + sum over active i of fw1T[i][j] ----
        {
            float acc = fb1r;
#pragma unroll 1
            for (int l = 0; l < 18; ++l) {
                unsigned long long mk = masks[l];
                while (mk) {   // uniform across block; 8-wide load batching
                    float f0 = 0.f, f1 = 0.f, f2 = 0.f, f3 = 0.f;
                    float f4 = 0.f, f5 = 0.f, f6 = 0.f, f7 = 0.f;
                    int c;
                    c = (int)__builtin_ctzll(mk); mk &= mk - 1;
                    f0 = fw1T[(c * 18 + l) * 256 + tid];
                    if (mk) { c = (int)__builtin_ctzll(mk); mk &= mk - 1;
                              f1 = fw1T[(c * 18 + l) * 256 + tid]; }
                    if (mk) { c = (int)__builtin_ctzll(mk); mk &= mk - 1;
                              f2 = fw1T[(c * 18 + l) * 256 + tid]; }
                    if (mk) { c = (int)__builtin_ctzll(mk); mk &= mk - 1;
                              f3 = fw1T[(c * 18 + l) * 256 + tid]; }
                    if (mk) { c = (int)__builtin_ctzll(mk); mk &= mk - 1;
                              f4 = fw1T[(c * 18 + l) * 256 + tid]; }
                    if (mk) { c = (int)__builtin_ctzll(mk); mk &= mk - 1;
                              f5 = fw1T[(c * 18 + l) * 256 + tid]; }
                    if (mk) { c = (int)__builtin_ctzll(mk); mk &= mk - 1;
                              f6 = fw1T[(c * 18 + l) * 256 + tid]; }
                    if (mk) { c = (int)__builtin_ctzll(mk); mk &= mk - 1;
                              f7 = fw1T[(c * 18 + l) * 256 + tid]; }
                    acc += f0; acc += f1; acc += f2; acc += f3;  // +0.0 is exact
                    acc += f4; acc += f5; acc += f6; acc += f7;
                }
            }
            float rs = (m4 > 1.0f) ? 1.0f : 0.0f;
            m4 = BETA * m4 + acc - rs;
            s4[tid] = (m4 > 1.0f) ? 1.0f : 0.0f;
        }
        __syncthreads();

        // ---- fc2: 10 outputs, 8 partial chunks of 32 each ----
        if (tid < 80) {
            const int j = tid >> 3, ch = tid & 7;
            const float* wrow = fw2 + j * 256 + ch * 32;
            const float* srow = s4 + ch * 32;
            float p = 0.f;
#pragma unroll
            for (int i = 0; i < 32; ++i) p += srow[i] * wrow[i];
            parts[tid] = p;
        }
        __syncthreads();
        if (tid < 10) {
            float h = fb2r;
#pragma unroll
            for (int cpt = 0; cpt < 8; ++cpt) h += parts[tid * 8 + cpt];
            float rs = (m5 > 1.0f) ? 1.0f : 0.0f;
            m5 = BETA * m5 + h - rs;
            out[t * 10240 + out_b + tid] = (m5 > 1.0f) ? 1.0f : 0.0f;
        }
        __syncthreads();   // parts/s4 safe: next writes are >=2 barriers away,
                           // but keep one barrier so conv1's s1 writes can't
                           // race the fc2 phases' s4/parts reads... (s1 vs s4
                           // are distinct buffers; this barrier orders out[]
                           // readers vs next-step writers of parts)
    }
}

extern "C" void kernel_launch(void* const* d_in, const int* in_sizes, int n_in,
                              void* d_out, int out_size, void* d_ws, size_t ws_size,
                              hipStream_t stream) {
    const float* x   = (const float*)d_in[0];
    const float* w1  = (const float*)d_in[1];
    const float* b1  = (const float*)d_in[2];
    const float* w2  = (const float*)d_in[3];
    const float* b2  = (const float*)d_in[4];
    const float* w3  = (const float*)d_in[5];
    const float* b3  = (const float*)d_in[6];
    const float* fw1 = (const float*)d_in[7];
    const float* fb1 = (const float*)d_in[8];
    const float* fw2 = (const float*)d_in[9];
    const float* fb2 = (const float*)d_in[10];
    float* out  = (float*)d_out;
    float* fw1T = (float*)d_ws;   // 1152*256*4 = 1.18 MB

    dim3 tb(32, 8);
    dim3 tg(1152 / 32, 256 / 32);
    transpose_fw1<<<tg, tb, 0, stream>>>(fw1, fw1T);
    snn_main<<<1024, 256, 0, stream>>>(x, w1, b1, w2, b2, w3, b3,
                                       fw1T, fb1, fw2, fb2, out);
}

// Round 4
// 916.849 us; speedup vs baseline: 3.8293x; 1.3005x over previous
//
#include <hip/hip_runtime.h>
#include <stdint.h>

#define BETA 0.9f

// ---------------------------------------------------------------------------
// Kernel 1: transpose fw1 (256, 1152) -> fw1T (1152, 256) so the sparse fc1
// row-gather is coalesced (row i = 256 contiguous floats = 1KB per wave read).
// ---------------------------------------------------------------------------
__global__ void transpose_fw1(const float* __restrict__ A, float* __restrict__ At) {
    __shared__ float tile[32][33];
    const int i0 = blockIdx.x * 32;   // i dim (1152)
    const int j0 = blockIdx.y * 32;   // j dim (256)
    const int tx = threadIdx.x, ty = threadIdx.y;
    for (int r = ty; r < 32; r += 8)
        tile[r][tx] = A[(j0 + r) * 1152 + i0 + tx];      // coalesced read over i
    __syncthreads();
    for (int r = ty; r < 32; r += 8)
        At[(i0 + r) * 256 + j0 + tx] = tile[tx][r];      // coalesced write over j
}

// ---------------------------------------------------------------------------
// Kernel 2: whole SNN, one block (256 threads) per batch element. R4:
//  - per-row spike bitmasks (rm1/rm2, parity double-buffered) replace the
//    7-read + 13-op + ballot nz probe with 1 broadcast read + scalar test;
//    silent rows skip their window reads entirely.
//  - fc2 fused into one phase via width-16 shuffle reduction: 6 -> 4
//    barriers per step, parts[] LDS removed.
// ---------------------------------------------------------------------------
__global__ __launch_bounds__(256, 4) void snn_main(
    const float* __restrict__ x,      // (1024, 1, 30, 100)
    const float* __restrict__ w1, const float* __restrict__ b1,
    const float* __restrict__ w2, const float* __restrict__ b2,
    const float* __restrict__ w3, const float* __restrict__ b3,
    const float* __restrict__ fw1T,   // (1152, 256) transposed
    const float* __restrict__ fb1,
    const float* __restrict__ fw2, const float* __restrict__ fb2,
    float* __restrict__ out)          // (100, 1024, 10)
{
    const int b    = blockIdx.x;
    const int tid  = threadIdx.x;
    const int lane = tid & 63;
    const int wave = tid >> 6;

    __shared__ float s1[16 * 24 + 4];   // +4: lg2=7 reads win[6] (unused in FMA)
    __shared__ float s2[32 * 20 + 4];   // +4: wave3 reads win[5..6] (unused)
    __shared__ float w2L[16 * 5 * 32];  // [(ci*5+k)*32 + c2]  10 KB
    __shared__ float w3L[32 * 3 * 64];  // [(ci*3+k)*64 + c3]  24 KB
    __shared__ unsigned long long masks[18];  // s3 spikes per l (bit = channel)
    __shared__ float s4[256];
    __shared__ unsigned int rm1[2][16]; // s1 row spike masks (bit l), by t-parity
    __shared__ unsigned int rm2[2][32]; // s2 row spike masks (bit l), by t-parity

    // ---- static per-thread roles ----
    const int c1 = tid & 15;            // conv1: channel
    const int l1 = tid >> 4;            // conv1: l (0..15); + l1+16 for tid<128
    const int c2 = tid & 31;            // conv2: channel
    const int lg2 = tid >> 5;           // conv2: l-group 0..7
    const int l02 = (lg2 < 4) ? 3 * lg2 : 12 + 2 * (lg2 - 4);
    const int nl2 = (lg2 < 4) ? 3 : 2;  // uniform within each wave
    const int c3 = lane;                // conv3: channel = lane
    const int l03 = wave * 5;           // conv3: l-range start (wave-uniform)
    const int nl3 = (wave < 3) ? 5 : 3; // 5,5,5,3 -> 18

    // wave-level union windows for the row-skip tests (wave-uniform consts)
    const unsigned wmask2 = (wave == 0) ? 0x3FFu :      // l 0..9
                            (wave == 1) ? 0xFFC0u :     // l 6..15
                            (wave == 2) ? 0xFF000u :    // l 12..19
                                          0xFF0000u;    // l 16..23
    const unsigned wmask3 = (wave == 0) ? 0x7Fu :       // l 0..6
                            (wave == 1) ? 0xFE0u :      // l 5..11
                            (wave == 2) ? 0x1FC00u :    // l 10..16
                                          0xF8000u;     // l 15..19

    // ---- stage weights into LDS (lane-transposed layouts) ----
    for (int i = tid; i < 16 * 5 * 32; i += 256) {
        const int cc = i & 31, r = i >> 5;          // r = ci*5+k
        w2L[i] = w2[cc * 80 + r];
    }
    for (int i = tid; i < 32 * 3 * 64; i += 256) {
        const int cc = i & 63, r = i >> 6;          // r = ci*3+k
        w3L[i] = w3[cc * 96 + r];
    }
    if (tid < 16) { rm1[0][tid] = 0u; rm1[1][tid] = 0u; }
    if (tid < 32) { rm2[0][tid] = 0u; rm2[1][tid] = 0u; }

    // ---- small per-thread register state ----
    float w1r[7];
#pragma unroll
    for (int k = 0; k < 7; ++k) w1r[k] = w1[c1 * 7 + k];
    const float b1r = b1[c1];
    const float b2r = b2[c2];
    const float b3r = b3[c3];
    const float fb1r = fb1[tid];
    const float fb2r = (tid < 160 && (tid & 15) == 0) ? fb2[tid >> 4] : 0.0f;

    float m1a = 0.f, m1b = 0.f;
    float m2[3] = {0.f, 0.f, 0.f};
    float m3[5] = {0.f, 0.f, 0.f, 0.f, 0.f};
    float m4 = 0.f, m5 = 0.f;

    const float* xb = x + b * 3000;
    const int out_b = b * 10;

    // x register prefetch for t=0 (overlaps the staging barrier)
    float xr[7], xr2[7];
#pragma unroll
    for (int k = 0; k < 7; ++k) xr[k] = xb[(l1 + k) * 100];
#pragma unroll
    for (int k = 0; k < 7; ++k) xr2[k] = (tid < 128) ? xb[(16 + l1 + k) * 100] : 0.0f;

    __syncthreads();   // staging -> compute

    for (int t = 0; t < 100; ++t) {
        const int pb = t & 1, pn = pb ^ 1;

        // ---- conv1 + LIF1 (x from prefetched registers) ----
        {
            unsigned bits = 0u;
            float h = b1r;
#pragma unroll
            for (int k = 0; k < 7; ++k) h += xr[k] * w1r[k];
            float rs = (m1a > 1.0f) ? 1.0f : 0.0f;
            m1a = BETA * m1a + h - rs;
            float sa = (m1a > 1.0f) ? 1.0f : 0.0f;
            s1[c1 * 24 + l1] = sa;
            if (sa != 0.0f) bits |= 1u << l1;
            if (tid < 128) {
                float h2 = b1r;
#pragma unroll
                for (int k = 0; k < 7; ++k) h2 += xr2[k] * w1r[k];
                float r2 = (m1b > 1.0f) ? 1.0f : 0.0f;
                m1b = BETA * m1b + h2 - r2;
                float sb = (m1b > 1.0f) ? 1.0f : 0.0f;
                s1[c1 * 24 + 16 + l1] = sb;
                if (sb != 0.0f) bits |= 1u << (16 + l1);
            }
            if (bits) atomicOr(&rm1[pb][c1], bits);
        }
        // prefetch x for t+1 (hidden under conv2..fc2 of this step)
        {
            const int tt = (t < 99) ? t + 1 : 99;
#pragma unroll
            for (int k = 0; k < 7; ++k) xr[k] = xb[(l1 + k) * 100 + tt];
            if (tid < 128) {
#pragma unroll
                for (int k = 0; k < 7; ++k) xr2[k] = xb[(16 + l1 + k) * 100 + tt];
            }
        }
        __syncthreads();   // b1

        // ---- conv2 + LIF2 (rowmask skip) ----
        {
            if (tid < 16) rm1[pn][tid] = 0u;   // zero other parity for t+1
            float h[3] = {b2r, b2r, b2r};
#pragma unroll
            for (int ci = 0; ci < 16; ++ci) {
                const unsigned rmv =
                    __builtin_amdgcn_readfirstlane(rm1[pb][ci]);
                if ((rmv & wmask2) == 0u) continue;   // exact: skipped terms 0*w
                float win[7];
#pragma unroll
                for (int r = 0; r < 7; ++r) win[r] = s1[ci * 24 + l02 + r];
                float wk[5];
#pragma unroll
                for (int k = 0; k < 5; ++k) wk[k] = w2L[(ci * 5 + k) * 32 + c2];
#pragma unroll
                for (int li = 0; li < 3; ++li)
                    if (li < nl2)
#pragma unroll
                        for (int k = 0; k < 5; ++k) h[li] += win[li + k] * wk[k];
            }
            unsigned bits = 0u;
#pragma unroll
            for (int li = 0; li < 3; ++li)
                if (li < nl2) {
                    float rs = (m2[li] > 1.0f) ? 1.0f : 0.0f;
                    m2[li] = BETA * m2[li] + h[li] - rs;
                    float sp = (m2[li] > 1.0f) ? 1.0f : 0.0f;
                    s2[c2 * 20 + l02 + li] = sp;
                    if (sp != 0.0f) bits |= 1u << (l02 + li);
                }
            if (bits) atomicOr(&rm2[pb][c2], bits);
        }
        __syncthreads();   // b2

        // ---- conv3 + LIF3 -> spike bitmasks (rowmask skip) ----
        {
            if (tid < 32) rm2[pn][tid] = 0u;   // zero other parity for t+1
            float h[5] = {b3r, b3r, b3r, b3r, b3r};
#pragma unroll
            for (int ci = 0; ci < 32; ++ci) {
                const unsigned rmv =
                    __builtin_amdgcn_readfirstlane(rm2[pb][ci]);
                if ((rmv & wmask3) == 0u) continue;
                float win[7];
#pragma unroll
                for (int r = 0; r < 7; ++r) win[r] = s2[ci * 20 + l03 + r];
                float wk[3];
#pragma unroll
                for (int k = 0; k < 3; ++k) wk[k] = w3L[(ci * 3 + k) * 64 + c3];
#pragma unroll
                for (int li = 0; li < 5; ++li)
                    if (li < nl3)
#pragma unroll
                        for (int k = 0; k < 3; ++k) h[li] += win[li + k] * wk[k];
            }
#pragma unroll
            for (int li = 0; li < 5; ++li)
                if (li < nl3) {   // wave-uniform -> ballot safe
                    float rs = (m3[li] > 1.0f) ? 1.0f : 0.0f;
                    m3[li] = BETA * m3[li] + h[li] - rs;
                    float s = (m3[li] > 1.0f) ? 1.0f : 0.0f;
                    unsigned long long mk = __ballot(s != 0.0f);
                    if (lane == 0) masks[l03 + li] = mk;
                }
        }
        __syncthreads();   // b3

        // ---- fc1 sparse: h[j] = fb1[j] + sum over active i of fw1T[i][j] ----
        {
            float acc = fb1r;
#pragma unroll 1
            for (int l = 0; l < 18; ++l) {
                unsigned long long mk = masks[l];
                while (mk) {   // uniform across block; 8-wide load batching
                    float f0 = 0.f, f1 = 0.f, f2 = 0.f, f3 = 0.f;
                    float f4 = 0.f, f5 = 0.f, f6 = 0.f, f7 = 0.f;
                    int c;
                    c = (int)__builtin_ctzll(mk); mk &= mk - 1;
                    f0 = fw1T[(c * 18 + l) * 256 + tid];
                    if (mk) { c = (int)__builtin_ctzll(mk); mk &= mk - 1;
                              f1 = fw1T[(c * 18 + l) * 256 + tid]; }
                    if (mk) { c = (int)__builtin_ctzll(mk); mk &= mk - 1;
                              f2 = fw1T[(c * 18 + l) * 256 + tid]; }
                    if (mk) { c = (int)__builtin_ctzll(mk); mk &= mk - 1;
                              f3 = fw1T[(c * 18 + l) * 256 + tid]; }
                    if (mk) { c = (int)__builtin_ctzll(mk); mk &= mk - 1;
                              f4 = fw1T[(c * 18 + l) * 256 + tid]; }
                    if (mk) { c = (int)__builtin_ctzll(mk); mk &= mk - 1;
                              f5 = fw1T[(c * 18 + l) * 256 + tid]; }
                    if (mk) { c = (int)__builtin_ctzll(mk); mk &= mk - 1;
                              f6 = fw1T[(c * 18 + l) * 256 + tid]; }
                    if (mk) { c = (int)__builtin_ctzll(mk); mk &= mk - 1;
                              f7 = fw1T[(c * 18 + l) * 256 + tid]; }
                    acc += f0; acc += f1; acc += f2; acc += f3;  // +0.0 exact
                    acc += f4; acc += f5; acc += f6; acc += f7;
                }
            }
            float rs = (m4 > 1.0f) ? 1.0f : 0.0f;
            m4 = BETA * m4 + acc - rs;
            s4[tid] = (m4 > 1.0f) ? 1.0f : 0.0f;
        }
        __syncthreads();   // b4

        // ---- fc2 fused: 10 outputs, 16 lanes each, shuffle reduce ----
        if (tid < 160) {
            const int j = tid >> 4, ch = tid & 15;
            const float* wrow = fw2 + j * 256;
            float p = 0.f;
#pragma unroll
            for (int i = 0; i < 16; ++i)
                p += s4[i * 16 + ch] * wrow[i * 16 + ch];
            p += __shfl_xor(p, 8, 16);
            p += __shfl_xor(p, 4, 16);
            p += __shfl_xor(p, 2, 16);
            p += __shfl_xor(p, 1, 16);
            if (ch == 0) {
                float h = fb2r + p;
                float rs = (m5 > 1.0f) ? 1.0f : 0.0f;
                m5 = BETA * m5 + h - rs;
                out[t * 10240 + out_b + j] = (m5 > 1.0f) ? 1.0f : 0.0f;
            }
        }
        // no end-of-loop barrier: next phase to write s4 is fc1 (behind b1..b3);
        // next writers of s1/rm1 (conv1) don't conflict with fc2's s4/fw2 reads.
    }
}

extern "C" void kernel_launch(void* const* d_in, const int* in_sizes, int n_in,
                              void* d_out, int out_size, void* d_ws, size_t ws_size,
                              hipStream_t stream) {
    const float* x   = (const float*)d_in[0];
    const float* w1  = (const float*)d_in[1];
    const float* b1  = (const float*)d_in[2];
    const float* w2  = (const float*)d_in[3];
    const float* b2  = (const float*)d_in[4];
    const float* w3  = (const float*)d_in[5];
    const float* b3  = (const float*)d_in[6];
    const float* fw1 = (const float*)d_in[7];
    const float* fb1 = (const float*)d_in[8];
    const float* fw2 = (const float*)d_in[9];
    const float* fb2 = (const float*)d_in[10];
    float* out  = (float*)d_out;
    float* fw1T = (float*)d_ws;   // 1152*256*4 = 1.18 MB

    dim3 tb(32, 8);
    dim3 tg(1152 / 32, 256 / 32);
    transpose_fw1<<<tg, tb, 0, stream>>>(fw1, fw1T);
    snn_main<<<1024, 256, 0, stream>>>(x, w1, b1, w2, b2, w3, b3,
                                       fw1T, fb1, fw2, fb2, out);
}

// Round 5
// 848.448 us; speedup vs baseline: 4.1380x; 1.0806x over previous
//
#include <hip/hip_runtime.h>
#include <stdint.h>

#define BETA 0.9f

// ---------------------------------------------------------------------------
// Kernel 1: transpose fw1 (256, 1152) -> fw1T (1152, 256) so the sparse fc1
// row-gather is coalesced (row i = 256 contiguous floats = 1KB per wave read).
// ---------------------------------------------------------------------------
__global__ void transpose_fw1(const float* __restrict__ A, float* __restrict__ At) {
    __shared__ float tile[32][33];
    const int i0 = blockIdx.x * 32;   // i dim (1152)
    const int j0 = blockIdx.y * 32;   // j dim (256)
    const int tx = threadIdx.x, ty = threadIdx.y;
    for (int r = ty; r < 32; r += 8)
        tile[r][tx] = A[(j0 + r) * 1152 + i0 + tx];      // coalesced read over i
    __syncthreads();
    for (int r = ty; r < 32; r += 8)
        At[(i0 + r) * 256 + j0 + tx] = tile[tx][r];      // coalesced write over j
}

// ---------------------------------------------------------------------------
// Kernel 2: whole SNN, one block (256 threads) per batch element. R5:
//  - conv3 is a spike-driven gather off per-position channel masks cm2[l]
//    (wave-uniform window -> scalar mask walk, ds_read imm offsets); the s2
//    value array is gone (spike value is 1.0, only masks matter).
//  - fc1 mask walk scalarized via readfirstlane (s_ff1 + scalar addresses).
//  - fw2 cached in 16 VGPRs per fc2 thread.
// ---------------------------------------------------------------------------
__global__ __launch_bounds__(256, 4) void snn_main(
    const float* __restrict__ x,      // (1024, 1, 30, 100)
    const float* __restrict__ w1, const float* __restrict__ b1,
    const float* __restrict__ w2, const float* __restrict__ b2,
    const float* __restrict__ w3, const float* __restrict__ b3,
    const float* __restrict__ fw1T,   // (1152, 256) transposed
    const float* __restrict__ fb1,
    const float* __restrict__ fw2, const float* __restrict__ fb2,
    float* __restrict__ out)          // (100, 1024, 10)
{
    const int b    = blockIdx.x;
    const int tid  = threadIdx.x;
    const int lane = tid & 63;
    const int wave = tid >> 6;

    __shared__ float s1[16 * 24 + 4];   // +4: lg2=7 r=6 over-read (unused in FMA)
    __shared__ float w2L[16 * 5 * 32];  // [(ci*5+k)*32 + c2]  10 KB
    __shared__ float w3L[32 * 3 * 64];  // [(ci*3+k)*64 + c3]  24 KB
    __shared__ unsigned long long masks[18];  // s3 spikes per l (bit = channel)
    __shared__ float s4[256];
    __shared__ unsigned int rm1[2][16]; // s1 row spike masks (bit l), by t-parity
    __shared__ unsigned int cm2[2][20]; // s2 per-l channel masks (bit c2), parity

    // ---- static per-thread roles ----
    const int c1 = tid & 15;            // conv1: channel
    const int l1 = tid >> 4;            // conv1: l (0..15); + l1+16 for tid<128
    const int c2 = tid & 31;            // conv2: channel
    const int lg2 = tid >> 5;           // conv2: l-group 0..7
    const int l02 = (lg2 < 4) ? 3 * lg2 : 12 + 2 * (lg2 - 4);
    const int nl2 = (lg2 < 4) ? 3 : 2;  // uniform within each wave
    const int c3 = lane;                // conv3: out channel = lane (0..63)
    const int l03 = wave * 5;           // conv3: l-range start (wave-uniform)
    const int nl3 = (wave < 3) ? 5 : 3; // 5,5,5,3 -> 18

    // wave-level union windows for the conv2 row-skip (wave-uniform consts)
    const unsigned wmask2 = (wave == 0) ? 0x3FFu :      // l 0..9
                            (wave == 1) ? 0xFFC0u :     // l 6..15
                            (wave == 2) ? 0xFF000u :    // l 12..19
                                          0xFF0000u;    // l 16..23

    // ---- stage weights into LDS (lane-transposed layouts) ----
    for (int i = tid; i < 16 * 5 * 32; i += 256) {
        const int cc = i & 31, r = i >> 5;          // r = ci*5+k
        w2L[i] = w2[cc * 80 + r];
    }
    for (int i = tid; i < 32 * 3 * 64; i += 256) {
        const int cc = i & 63, r = i >> 6;          // r = ci*3+k
        w3L[i] = w3[cc * 96 + r];
    }
    if (tid < 16) { rm1[0][tid] = 0u; rm1[1][tid] = 0u; }
    if (tid < 20) { cm2[0][tid] = 0u; cm2[1][tid] = 0u; }
    if (tid < 4)  s1[384 + tid] = 0.0f;

    // ---- small per-thread register state ----
    float w1r[7];
#pragma unroll
    for (int k = 0; k < 7; ++k) w1r[k] = w1[c1 * 7 + k];
    const float b1r = b1[c1];
    const float b2r = b2[c2];
    const float b3r = b3[c3];
    const float fb1r = fb1[tid];
    const int jf = tid >> 4, chf = tid & 15;         // fc2 roles (tid<160)
    const float fb2r = (tid < 160 && chf == 0) ? fb2[jf] : 0.0f;
    float fw2r[16];
    if (tid < 160) {
#pragma unroll
        for (int i = 0; i < 16; ++i) fw2r[i] = fw2[jf * 256 + i * 16 + chf];
    }

    float m1a = 0.f, m1b = 0.f;
    float m2[3] = {0.f, 0.f, 0.f};
    float m3[5] = {0.f, 0.f, 0.f, 0.f, 0.f};
    float m4 = 0.f, m5 = 0.f;

    const float* xb = x + b * 3000;
    const int out_b = b * 10;

    // x register prefetch for t=0 (overlaps the staging barrier)
    float xr[7], xr2[7];
#pragma unroll
    for (int k = 0; k < 7; ++k) xr[k] = xb[(l1 + k) * 100];
#pragma unroll
    for (int k = 0; k < 7; ++k) xr2[k] = (tid < 128) ? xb[(16 + l1 + k) * 100] : 0.0f;

    __syncthreads();   // staging -> compute

    for (int t = 0; t < 100; ++t) {
        const int pb = t & 1, pn = pb ^ 1;

        // ---- conv1 + LIF1 (x from prefetched registers) ----
        {
            unsigned bits = 0u;
            float h = b1r;
#pragma unroll
            for (int k = 0; k < 7; ++k) h += xr[k] * w1r[k];
            float rs = (m1a > 1.0f) ? 1.0f : 0.0f;
            m1a = BETA * m1a + h - rs;
            float sa = (m1a > 1.0f) ? 1.0f : 0.0f;
            s1[c1 * 24 + l1] = sa;
            if (sa != 0.0f) bits |= 1u << l1;
            if (tid < 128) {
                float h2 = b1r;
#pragma unroll
                for (int k = 0; k < 7; ++k) h2 += xr2[k] * w1r[k];
                float r2 = (m1b > 1.0f) ? 1.0f : 0.0f;
                m1b = BETA * m1b + h2 - r2;
                float sb = (m1b > 1.0f) ? 1.0f : 0.0f;
                s1[c1 * 24 + 16 + l1] = sb;
                if (sb != 0.0f) bits |= 1u << (16 + l1);
            }
            if (bits) atomicOr(&rm1[pb][c1], bits);
        }
        // prefetch x for t+1 (hidden under conv2..fc2 of this step)
        {
            const int tt = (t < 99) ? t + 1 : 99;
#pragma unroll
            for (int k = 0; k < 7; ++k) xr[k] = xb[(l1 + k) * 100 + tt];
            if (tid < 128) {
#pragma unroll
                for (int k = 0; k < 7; ++k) xr2[k] = xb[(16 + l1 + k) * 100 + tt];
            }
        }
        __syncthreads();   // b1

        // ---- conv2 + LIF2 (rm1 row-skip) -> spikes into cm2 masks ----
        {
            if (tid < 16) rm1[pn][tid] = 0u;   // zero other parity for t+1
            if (tid < 20) cm2[pn][tid] = 0u;
            float h[3] = {b2r, b2r, b2r};
#pragma unroll
            for (int ci = 0; ci < 16; ++ci) {
                const unsigned rmv =
                    __builtin_amdgcn_readfirstlane(rm1[pb][ci]);
                if ((rmv & wmask2) == 0u) continue;   // exact: skipped terms 0*w
                float win[7];
#pragma unroll
                for (int r = 0; r < 7; ++r) win[r] = s1[ci * 24 + l02 + r];
                float wk[5];
#pragma unroll
                for (int k = 0; k < 5; ++k) wk[k] = w2L[(ci * 5 + k) * 32 + c2];
#pragma unroll
                for (int li = 0; li < 3; ++li)
                    if (li < nl2)
#pragma unroll
                        for (int k = 0; k < 5; ++k) h[li] += win[li + k] * wk[k];
            }
#pragma unroll
            for (int li = 0; li < 3; ++li)
                if (li < nl2) {
                    float rs = (m2[li] > 1.0f) ? 1.0f : 0.0f;
                    m2[li] = BETA * m2[li] + h[li] - rs;
                    if (m2[li] > 1.0f) atomicOr(&cm2[pb][l02 + li], 1u << c2);
                }
        }
        __syncthreads();   // b2

        // ---- conv3 + LIF3: spike-driven gather (wave-uniform window) ----
        {
            float h[5] = {b3r, b3r, b3r, b3r, b3r};
            const int wcnt = nl3 + 2;      // window positions (wave-uniform)
#pragma unroll
            for (int wl = 0; wl < 7; ++wl) {
                if (wl >= wcnt) break;     // scalar-uniform exit
                unsigned cm = __builtin_amdgcn_readfirstlane(cm2[pb][l03 + wl]);
                while (cm) {               // scalar mask walk
                    const int ci = (int)__builtin_ctz(cm); cm &= cm - 1;
                    const float* wp = &w3L[ci * 192 + c3];   // + k*64
#pragma unroll
                    for (int k = 0; k < 3; ++k) {
                        const int li = wl - k;               // compile-time
                        if (li >= 0 && li < 5)
                            if (li < nl3)                    // scalar runtime
                                h[li] += wp[k * 64];         // ds_read imm offset
                    }
                }
            }
#pragma unroll
            for (int li = 0; li < 5; ++li)
                if (li < nl3) {   // wave-uniform -> ballot safe
                    float rs = (m3[li] > 1.0f) ? 1.0f : 0.0f;
                    m3[li] = BETA * m3[li] + h[li] - rs;
                    float s = (m3[li] > 1.0f) ? 1.0f : 0.0f;
                    unsigned long long mk = __ballot(s != 0.0f);
                    if (lane == 0) masks[l03 + li] = mk;
                }
        }
        __syncthreads();   // b3

        // ---- fc1 sparse: scalar mask walk + coalesced row gather ----
        {
            float acc = fb1r;
#pragma unroll 1
            for (int l = 0; l < 18; ++l) {
                const unsigned* mp = (const unsigned*)&masks[l];
                const unsigned mlo = __builtin_amdgcn_readfirstlane(mp[0]);
                const unsigned mhi = __builtin_amdgcn_readfirstlane(mp[1]);
                unsigned long long mk = ((unsigned long long)mhi << 32) | mlo;
                while (mk) {   // uniform; 8-wide load batching
                    float f0 = 0.f, f1 = 0.f, f2 = 0.f, f3 = 0.f;
                    float f4 = 0.f, f5 = 0.f, f6 = 0.f, f7 = 0.f;
                    int c;
                    c = (int)__builtin_ctzll(mk); mk &= mk - 1;
                    f0 = fw1T[(c * 18 + l) * 256 + tid];
                    if (mk) { c = (int)__builtin_ctzll(mk); mk &= mk - 1;
                              f1 = fw1T[(c * 18 + l) * 256 + tid]; }
                    if (mk) { c = (int)__builtin_ctzll(mk); mk &= mk - 1;
                              f2 = fw1T[(c * 18 + l) * 256 + tid]; }
                    if (mk) { c = (int)__builtin_ctzll(mk); mk &= mk - 1;
                              f3 = fw1T[(c * 18 + l) * 256 + tid]; }
                    if (mk) { c = (int)__builtin_ctzll(mk); mk &= mk - 1;
                              f4 = fw1T[(c * 18 + l) * 256 + tid]; }
                    if (mk) { c = (int)__builtin_ctzll(mk); mk &= mk - 1;
                              f5 = fw1T[(c * 18 + l) * 256 + tid]; }
                    if (mk) { c = (int)__builtin_ctzll(mk); mk &= mk - 1;
                              f6 = fw1T[(c * 18 + l) * 256 + tid]; }
                    if (mk) { c = (int)__builtin_ctzll(mk); mk &= mk - 1;
                              f7 = fw1T[(c * 18 + l) * 256 + tid]; }
                    acc += f0; acc += f1; acc += f2; acc += f3;  // +0.0 exact
                    acc += f4; acc += f5; acc += f6; acc += f7;
                }
            }
            float rs = (m4 > 1.0f) ? 1.0f : 0.0f;
            m4 = BETA * m4 + acc - rs;
            s4[tid] = (m4 > 1.0f) ? 1.0f : 0.0f;
        }
        __syncthreads();   // b4

        // ---- fc2 fused: 10 outputs, 16 lanes each, shuffle reduce ----
        if (tid < 160) {
            float p = 0.f;
#pragma unroll
            for (int i = 0; i < 16; ++i)
                p += s4[i * 16 + chf] * fw2r[i];
            p += __shfl_xor(p, 8, 16);
            p += __shfl_xor(p, 4, 16);
            p += __shfl_xor(p, 2, 16);
            p += __shfl_xor(p, 1, 16);
            if (chf == 0) {
                float h = fb2r + p;
                float rs = (m5 > 1.0f) ? 1.0f : 0.0f;
                m5 = BETA * m5 + h - rs;
                out[t * 10240 + out_b + jf] = (m5 > 1.0f) ? 1.0f : 0.0f;
            }
        }
        // no trailing barrier: fc2's s4 reads are >=3 barriers from the next
        // s4 writer (fc1 of t+1); conv1 of t+1 touches disjoint buffers.
    }
}

extern "C" void kernel_launch(void* const* d_in, const int* in_sizes, int n_in,
                              void* d_out, int out_size, void* d_ws, size_t ws_size,
                              hipStream_t stream) {
    const float* x   = (const float*)d_in[0];
    const float* w1  = (const float*)d_in[1];
    const float* b1  = (const float*)d_in[2];
    const float* w2  = (const float*)d_in[3];
    const float* b2  = (const float*)d_in[4];
    const float* w3  = (const float*)d_in[5];
    const float* b3  = (const float*)d_in[6];
    const float* fw1 = (const float*)d_in[7];
    const float* fb1 = (const float*)d_in[8];
    const float* fw2 = (const float*)d_in[9];
    const float* fb2 = (const float*)d_in[10];
    float* out  = (float*)d_out;
    float* fw1T = (float*)d_ws;   // 1152*256*4 = 1.18 MB

    dim3 tb(32, 8);
    dim3 tg(1152 / 32, 256 / 32);
    transpose_fw1<<<tg, tb, 0, stream>>>(fw1, fw1T);
    snn_main<<<1024, 256, 0, stream>>>(x, w1, b1, w2, b2, w3, b3,
                                       fw1T, fb1, fw2, fb2, out);
}

// Round 6
// 741.396 us; speedup vs baseline: 4.7355x; 1.1444x over previous
//
#include <hip/hip_runtime.h>
#include <stdint.h>

#define BETA 0.9f

// ---------------------------------------------------------------------------
// Kernel 1: transpose fw1 (256, 1152) -> fw1T (1152, 256) so the fc1 spike
// row-gather is coalesced (row i = 256 contiguous floats = 1KB).
// ---------------------------------------------------------------------------
__global__ void transpose_fw1(const float* __restrict__ A, float* __restrict__ At) {
    __shared__ float tile[32][33];
    const int i0 = blockIdx.x * 32;   // i dim (1152)
    const int j0 = blockIdx.y * 32;   // j dim (256)
    const int tx = threadIdx.x, ty = threadIdx.y;
    for (int r = ty; r < 32; r += 8)
        tile[r][tx] = A[(j0 + r) * 1152 + i0 + tx];      // coalesced read over i
    __syncthreads();
    for (int r = ty; r < 32; r += 8)
        At[(i0 + r) * 256 + j0 + tx] = tile[tx][r];      // coalesced write over j
}

// ---------------------------------------------------------------------------
// Kernel 2: whole SNN. R6: 512-thread blocks carry TWO batch elements
// (2 blocks/CU, same 16 waves/CU; weights staged once per pair; barriers per
// element 4 -> 2.5). fc1 rebuilt: each wave walks l = ew mod 4 subset and
// reads whole 1KB rows as float4 (4x fewer load issues, 4 spikes in flight),
// partials reduced via pacc[4][256] (+1 cheap barrier).
// ---------------------------------------------------------------------------
__global__ __launch_bounds__(512, 4) void snn_main(
    const float* __restrict__ x,      // (1024, 1, 30, 100)
    const float* __restrict__ w1, const float* __restrict__ b1,
    const float* __restrict__ w2, const float* __restrict__ b2,
    const float* __restrict__ w3, const float* __restrict__ b3,
    const float* __restrict__ fw1T,   // (1152, 256) transposed
    const float* __restrict__ fb1,
    const float* __restrict__ fw2, const float* __restrict__ fb2,
    float* __restrict__ out)          // (100, 1024, 10)
{
    const int b    = blockIdx.x;
    const int tid  = threadIdx.x;
    const int e    = tid >> 8;          // element slot 0/1
    const int tl   = tid & 255;         // per-element thread id
    const int lane = tid & 63;          // hw-wave lane
    const int ew   = (tid >> 6) & 3;    // per-element wave 0..3

    __shared__ float w2L[16 * 5 * 32];  // [(ci*5+k)*32 + c2]  10 KB (shared)
    __shared__ float w3L[32 * 3 * 64];  // [(ci*3+k)*64 + c3]  24 KB (shared)
    __shared__ float pacc[2][4][256];   // fc1 per-wave partials  8 KB
    __shared__ float s1e[2][16 * 24 + 4];
    __shared__ float s4[2][256];
    __shared__ unsigned long long masks[2][18];  // s3 spikes (bit = channel)
    __shared__ unsigned int rm1[2][2][16];  // s1 row masks (bit l), t-parity
    __shared__ unsigned int cm2[2][2][20];  // s2 per-l channel masks, t-parity

    // ---- static per-thread roles (within element) ----
    const int c1 = tl & 15;             // conv1: channel
    const int l1 = tl >> 4;             // conv1: l (0..15); + l1+16 for tl<128
    const int c2 = tl & 31;             // conv2: channel
    const int lg2 = tl >> 5;            // conv2: l-group 0..7
    const int l02 = (lg2 < 4) ? 3 * lg2 : 12 + 2 * (lg2 - 4);
    const int nl2 = (lg2 < 4) ? 3 : 2;  // uniform within each wave
    const int c3 = lane;                // conv3: out channel
    const int l03 = ew * 5;             // conv3: l-range start (wave-uniform)
    const int nl3 = (ew < 3) ? 5 : 3;   // 5,5,5,3 -> 18

    const unsigned wmask2 = (ew == 0) ? 0x3FFu :      // l 0..9
                            (ew == 1) ? 0xFFC0u :     // l 6..15
                            (ew == 2) ? 0xFF000u :    // l 12..19
                                        0xFF0000u;    // l 16..23

    // ---- stage weights into LDS (shared by both elements) ----
    for (int i = tid; i < 16 * 5 * 32; i += 512) {
        const int cc = i & 31, r = i >> 5;          // r = ci*5+k
        w2L[i] = w2[cc * 80 + r];
    }
    for (int i = tid; i < 32 * 3 * 64; i += 512) {
        const int cc = i & 63, r = i >> 6;          // r = ci*3+k
        w3L[i] = w3[cc * 96 + r];
    }
    if (tl < 16) { rm1[e][0][tl] = 0u; rm1[e][1][tl] = 0u; }
    if (tl < 20) { cm2[e][0][tl] = 0u; cm2[e][1][tl] = 0u; }
    if (tl < 4)  s1e[e][384 + tl] = 0.0f;

    // ---- per-thread register state ----
    float w1r[7];
#pragma unroll
    for (int k = 0; k < 7; ++k) w1r[k] = w1[c1 * 7 + k];
    const float b1r = b1[c1];
    const float b2r = b2[c2];
    const float b3r = b3[c3];
    const float fb1r = fb1[tl];
    const int jf = tl >> 4, chf = tl & 15;           // fc2 roles (tl<160)
    const float fb2r = (tl < 160 && chf == 0) ? fb2[jf] : 0.0f;
    float fw2r[16];
    if (tl < 160) {
#pragma unroll
        for (int i = 0; i < 16; ++i) fw2r[i] = fw2[jf * 256 + i * 16 + chf];
    }

    float m1a = 0.f, m1b = 0.f;
    float m2[3] = {0.f, 0.f, 0.f};
    float m3[5] = {0.f, 0.f, 0.f, 0.f, 0.f};
    float m4 = 0.f, m5 = 0.f;

    const float* xb = x + (2 * b + e) * 3000;
    const int out_b = (2 * b + e) * 10;
    const float4* fw1Tv = reinterpret_cast<const float4*>(fw1T);

    // x register prefetch for t=0 (overlaps the staging barrier)
    float xr[7], xr2[7];
#pragma unroll
    for (int k = 0; k < 7; ++k) xr[k] = xb[(l1 + k) * 100];
#pragma unroll
    for (int k = 0; k < 7; ++k) xr2[k] = (tl < 128) ? xb[(16 + l1 + k) * 100] : 0.0f;

    __syncthreads();   // staging -> compute

    for (int t = 0; t < 100; ++t) {
        const int pb = t & 1, pn = pb ^ 1;

        // ---- conv1 + LIF1 (x from prefetched registers) ----
        {
            unsigned bits = 0u;
            float h = b1r;
#pragma unroll
            for (int k = 0; k < 7; ++k) h += xr[k] * w1r[k];
            float rs = (m1a > 1.0f) ? 1.0f : 0.0f;
            m1a = BETA * m1a + h - rs;
            float sa = (m1a > 1.0f) ? 1.0f : 0.0f;
            s1e[e][c1 * 24 + l1] = sa;
            if (sa != 0.0f) bits |= 1u << l1;
            if (tl < 128) {
                float h2 = b1r;
#pragma unroll
                for (int k = 0; k < 7; ++k) h2 += xr2[k] * w1r[k];
                float r2 = (m1b > 1.0f) ? 1.0f : 0.0f;
                m1b = BETA * m1b + h2 - r2;
                float sb = (m1b > 1.0f) ? 1.0f : 0.0f;
                s1e[e][c1 * 24 + 16 + l1] = sb;
                if (sb != 0.0f) bits |= 1u << (16 + l1);
            }
            if (bits) atomicOr(&rm1[e][pb][c1], bits);
        }
        // prefetch x for t+1 (hidden under conv2..fc2 of this step)
        {
            const int tt = (t < 99) ? t + 1 : 99;
#pragma unroll
            for (int k = 0; k < 7; ++k) xr[k] = xb[(l1 + k) * 100 + tt];
            if (tl < 128) {
#pragma unroll
                for (int k = 0; k < 7; ++k) xr2[k] = xb[(16 + l1 + k) * 100 + tt];
            }
        }
        __syncthreads();   // b1

        // ---- conv2 + LIF2 (rm1 row-skip) -> spikes into cm2 masks ----
        {
            if (tl < 16) rm1[e][pn][tl] = 0u;   // zero other parity for t+1
            if (tl < 20) cm2[e][pn][tl] = 0u;
            float h[3] = {b2r, b2r, b2r};
#pragma unroll
            for (int ci = 0; ci < 16; ++ci) {
                const unsigned rmv =
                    __builtin_amdgcn_readfirstlane(rm1[e][pb][ci]);
                if ((rmv & wmask2) == 0u) continue;   // exact: skipped terms 0*w
                float win[7];
#pragma unroll
                for (int r = 0; r < 7; ++r) win[r] = s1e[e][ci * 24 + l02 + r];
                float wk[5];
#pragma unroll
                for (int k = 0; k < 5; ++k) wk[k] = w2L[(ci * 5 + k) * 32 + c2];
#pragma unroll
                for (int li = 0; li < 3; ++li)
                    if (li < nl2)
#pragma unroll
                        for (int k = 0; k < 5; ++k) h[li] += win[li + k] * wk[k];
            }
#pragma unroll
            for (int li = 0; li < 3; ++li)
                if (li < nl2) {
                    float rs = (m2[li] > 1.0f) ? 1.0f : 0.0f;
                    m2[li] = BETA * m2[li] + h[li] - rs;
                    if (m2[li] > 1.0f) atomicOr(&cm2[e][pb][l02 + li], 1u << c2);
                }
        }
        __syncthreads();   // b2

        // ---- conv3 + LIF3: spike-driven gather (wave-uniform window) ----
        {
            float h[5] = {b3r, b3r, b3r, b3r, b3r};
            const int wcnt = nl3 + 2;      // window positions (wave-uniform)
#pragma unroll
            for (int wl = 0; wl < 7; ++wl) {
                if (wl >= wcnt) break;     // scalar-uniform exit
                unsigned cm = __builtin_amdgcn_readfirstlane(cm2[e][pb][l03 + wl]);
                while (cm) {               // scalar mask walk
                    const int ci = (int)__builtin_ctz(cm); cm &= cm - 1;
                    const float* wp = &w3L[ci * 192 + c3];   // + k*64
#pragma unroll
                    for (int k = 0; k < 3; ++k) {
                        const int li = wl - k;               // compile-time
                        if (li >= 0 && li < 5)
                            if (li < nl3)                    // scalar runtime
                                h[li] += wp[k * 64];         // ds_read imm offset
                    }
                }
            }
#pragma unroll
            for (int li = 0; li < 5; ++li)
                if (li < nl3) {   // wave-uniform -> ballot safe
                    float rs = (m3[li] > 1.0f) ? 1.0f : 0.0f;
                    m3[li] = BETA * m3[li] + h[li] - rs;
                    float s = (m3[li] > 1.0f) ? 1.0f : 0.0f;
                    unsigned long long mk = __ballot(s != 0.0f);
                    if (lane == 0) masks[e][l03 + li] = mk;
                }
        }
        __syncthreads();   // b3

        // ---- fc1 sparse: per-wave l-subset, float4 full-row gather ----
        {
            float4 acc4; acc4.x = acc4.y = acc4.z = acc4.w = 0.0f;
#pragma unroll 1
            for (int l = ew; l < 18; l += 4) {     // wave-uniform trip count
                const unsigned* mp = (const unsigned*)&masks[e][l];
                const unsigned mlo = __builtin_amdgcn_readfirstlane(mp[0]);
                const unsigned mhi = __builtin_amdgcn_readfirstlane(mp[1]);
                unsigned long long mk = ((unsigned long long)mhi << 32) | mlo;
                while (mk) {   // 4-wide float4 batching, whole row per wave
                    float4 f0, f1, f2, f3;
                    f0.x=f0.y=f0.z=f0.w=0.f; f1=f0; f2=f0; f3=f0;
                    int c;
                    c = (int)__builtin_ctzll(mk); mk &= mk - 1;
                    f0 = fw1Tv[(c * 18 + l) * 64 + lane];
                    if (mk) { c = (int)__builtin_ctzll(mk); mk &= mk - 1;
                              f1 = fw1Tv[(c * 18 + l) * 64 + lane]; }
                    if (mk) { c = (int)__builtin_ctzll(mk); mk &= mk - 1;
                              f2 = fw1Tv[(c * 18 + l) * 64 + lane]; }
                    if (mk) { c = (int)__builtin_ctzll(mk); mk &= mk - 1;
                              f3 = fw1Tv[(c * 18 + l) * 64 + lane]; }
                    acc4.x += f0.x; acc4.y += f0.y; acc4.z += f0.z; acc4.w += f0.w;
                    acc4.x += f1.x; acc4.y += f1.y; acc4.z += f1.z; acc4.w += f1.w;
                    acc4.x += f2.x; acc4.y += f2.y; acc4.z += f2.z; acc4.w += f2.w;
                    acc4.x += f3.x; acc4.y += f3.y; acc4.z += f3.z; acc4.w += f3.w;
                }
            }
            ((float4*)&pacc[e][ew][0])[lane] = acc4;   // partial for j=lane*4+k
        }
        __syncthreads();   // b4

        // ---- fc1 reduce + LIF4 (thread tl owns output j=tl) ----
        {
            float acc = fb1r + pacc[e][0][tl] + pacc[e][1][tl]
                             + pacc[e][2][tl] + pacc[e][3][tl];
            float rs = (m4 > 1.0f) ? 1.0f : 0.0f;
            m4 = BETA * m4 + acc - rs;
            s4[e][tl] = (m4 > 1.0f) ? 1.0f : 0.0f;
        }
        __syncthreads();   // b5

        // ---- fc2 fused: 10 outputs, 16 lanes each, shuffle reduce ----
        if (tl < 160) {
            float p = 0.f;
#pragma unroll
            for (int i = 0; i < 16; ++i)
                p += s4[e][i * 16 + chf] * fw2r[i];
            p += __shfl_xor(p, 8, 16);
            p += __shfl_xor(p, 4, 16);
            p += __shfl_xor(p, 2, 16);
            p += __shfl_xor(p, 1, 16);
            if (chf == 0) {
                float h = fb2r + p;
                float rs = (m5 > 1.0f) ? 1.0f : 0.0f;
                m5 = BETA * m5 + h - rs;
                out[t * 10240 + out_b + jf] = (m5 > 1.0f) ? 1.0f : 0.0f;
            }
        }
        // no trailing barrier: fc2's s4 reads are >=4 barriers from the next
        // s4 writer (reduce of t+1); conv1 of t+1 touches disjoint buffers.
    }
}

extern "C" void kernel_launch(void* const* d_in, const int* in_sizes, int n_in,
                              void* d_out, int out_size, void* d_ws, size_t ws_size,
                              hipStream_t stream) {
    const float* x   = (const float*)d_in[0];
    const float* w1  = (const float*)d_in[1];
    const float* b1  = (const float*)d_in[2];
    const float* w2  = (const float*)d_in[3];
    const float* b2  = (const float*)d_in[4];
    const float* w3  = (const float*)d_in[5];
    const float* b3  = (const float*)d_in[6];
    const float* fw1 = (const float*)d_in[7];
    const float* fb1 = (const float*)d_in[8];
    const float* fw2 = (const float*)d_in[9];
    const float* fb2 = (const float*)d_in[10];
    float* out  = (float*)d_out;
    float* fw1T = (float*)d_ws;   // 1152*256*4 = 1.18 MB

    dim3 tb(32, 8);
    dim3 tg(1152 / 32, 256 / 32);
    transpose_fw1<<<tg, tb, 0, stream>>>(fw1, fw1T);
    snn_main<<<512, 512, 0, stream>>>(x, w1, b1, w2, b2, w3, b3,
                                      fw1T, fb1, fw2, fb2, out);
}